// Round 2
// baseline (649.914 us; speedup 1.0000x reference)
//
#include <hip/hip_runtime.h>
#include <math.h>
#include <float.h>

#define BLK 256

// ---------------------------------------------------------------------------
// K0: fast exclusive scan of both count arrays. One block, 1024 threads.
// ---------------------------------------------------------------------------
__device__ __forceinline__ void scan_one(const int* __restrict__ cnt, int n,
                                         int* __restrict__ starts, int* wsum)
{
    const int t = threadIdx.x;
    const int chunk = (n + 1023) / 1024;
    const int base = t * chunk;

    int sum = 0;
    for (int k = 0; k < chunk; k++) {
        int idx = base + k;
        if (idx < n) sum += cnt[idx];
    }

    const int lane = t & 63, wid = t >> 6;
    int v = sum;
#pragma unroll
    for (int off = 1; off < 64; off <<= 1) {
        int y = __shfl_up(v, off);
        if (lane >= off) v += y;
    }
    if (lane == 63) wsum[wid] = v;
    __syncthreads();
    if (wid == 0) {
        int w = (lane < 16) ? wsum[lane] : 0;
#pragma unroll
        for (int off = 1; off < 16; off <<= 1) {
            int y = __shfl_up(w, off);
            if (lane >= off) w += y;
        }
        if (lane < 16) wsum[lane] = w;
    }
    __syncthreads();

    int thr_excl = ((wid > 0) ? wsum[wid - 1] : 0) + v - sum;
    int run = thr_excl;
    for (int k = 0; k < chunk; k++) {
        int idx = base + k;
        if (idx < n) { starts[idx] = run; run += cnt[idx]; }
    }
    if (t == 0) starts[n] = wsum[15];
    __syncthreads();
}

__global__ __launch_bounds__(1024) void scan2_kernel(
    const int* __restrict__ dag_cnt, int nd,
    const int* __restrict__ obs_cnt, int no,
    int* __restrict__ dag_starts, int* __restrict__ obs_starts)
{
    __shared__ int wsum[16];
    scan_one(dag_cnt, nd, dag_starts, wsum);
    scan_one(obs_cnt, no, obs_starts, wsum);
}

// ---------------------------------------------------------------------------
// K1: expand segment ids to per-node arrays (one block per segment).
// ---------------------------------------------------------------------------
__global__ __launch_bounds__(128) void expand_ids_kernel(
    const int* __restrict__ dag_starts, int nd,
    const int* __restrict__ obs_starts, int no,
    int* __restrict__ dag_ids, int* __restrict__ obs_ids)
{
    int seg = blockIdx.x;
    if (seg < nd) {
        int s = dag_starts[seg], e = dag_starts[seg + 1];
        for (int i = s + threadIdx.x; i < e; i += 128) dag_ids[i] = seg;
    } else {
        int g = seg - nd;
        int s = obs_starts[g], e = obs_starts[g + 1];
        for (int i = s + threadIdx.x; i < e; i += 128) obs_ids[i] = g;
    }
}

// ---------------------------------------------------------------------------
// K2: per-segment layer-1 partials (dag rows 37..68 no bias; glob rows 69..100 +b1).
// ---------------------------------------------------------------------------
__global__ __launch_bounds__(256) void seg_h1_kernel(
    const float* __restrict__ dag_sum, int nd,
    const float* __restrict__ glob_sum, int no,
    const float* __restrict__ W1, const float* __restrict__ b1,
    float* __restrict__ dag_h1, float* __restrict__ glob_h1)
{
    __shared__ float Wd[32 * 32];
    __shared__ float Wg[32 * 32];
    for (int t = threadIdx.x; t < 32 * 32; t += 256) {
        int k = t / 32, j = t % 32;
        Wd[t] = W1[(size_t)(37 + k) * 32 + j];
        Wg[t] = W1[(size_t)(69 + k) * 32 + j];
    }
    __syncthreads();

    int gid = blockIdx.x * 256 + threadIdx.x;
    int seg = gid / 32;
    int j   = gid % 32;
    if (seg >= nd + no) return;

    const float* srow;
    const float* Wl;
    float acc;
    float* outp;
    if (seg < nd) {
        srow = dag_sum + (size_t)seg * 32;
        Wl = Wd; acc = 0.f;
        outp = dag_h1 + (size_t)seg * 32 + j;
    } else {
        srow = glob_sum + (size_t)(seg - nd) * 32;
        Wl = Wg; acc = b1[j];
        outp = glob_h1 + (size_t)(seg - nd) * 32 + j;
    }
#pragma unroll
    for (int k = 0; k < 32; k++)
        acc = fmaf(srow[k], Wl[k * 32 + j], acc);
    *outp = acc;
}

// ---------------------------------------------------------------------------
// K3: main MLP. TWO nodes per thread, interleaved in ONE unrolled FMA stream
// so every scalar-loaded weight (SGPR operand of v_fmac_f32) is consumed by
// two FMAs. Rationale: weights (3905 floats) don't fit in SGPRs, so each wave
// re-streams ~500 s_load_x8/x16; with 1 node/thread the scalar stream + wave
// issue overhead was ~45% of the kernel (VALUBusy 78%). Halving wave count
// halves per-node scalar traffic. No LDS weights (DS pipe was the round-0
// bottleneck). __launch_bounds__(256,4) caps VGPR at 128 (expect ~90-110).
// ---------------------------------------------------------------------------
__global__ __launch_bounds__(BLK, 4) void mlp_score_kernel(
    const float* __restrict__ x, const float* __restrict__ emb,
    const float* __restrict__ dag_h1, const float* __restrict__ glob_h1,
    const int* __restrict__ dag_ids, const int* __restrict__ obs_ids,
    const int* __restrict__ mask,
    const float* __restrict__ W1, const float* __restrict__ W2,
    const float* __restrict__ b2, const float* __restrict__ W3,
    const float* __restrict__ b3, const float* __restrict__ W4,
    const float* __restrict__ b4,
    float* __restrict__ scores, float* __restrict__ blk_m,
    double* __restrict__ blk_s, int N)
{
    const int base = blockIdx.x * (2 * BLK) + threadIdx.x;
    const int i0a = base;
    const int i0b = base + BLK;
    const bool va = (i0a < N);
    const bool vb = (i0b < N);
    const int ia = va ? i0a : (N - 1);
    const int ib = vb ? i0b : (N - 1);

    // --- per-node loads: ids first (gathers depend on them) ---
    const int da = dag_ids[ia], db = dag_ids[ib];
    const int oa = obs_ids[ia], ob = obs_ids[ib];
    const int mka = mask[ia],  mkb = mask[ib];

    // --- layer-1 accumulators init from gathered per-segment partials ---
    // (b1 already folded into glob_h1). Loads consumed immediately to keep
    // live ranges short; scheduler hoists the issues.
    const float4* dha = (const float4*)(dag_h1 + (size_t)da * 32);
    const float4* gha = (const float4*)(glob_h1 + (size_t)oa * 32);
    const float4* dhb = (const float4*)(dag_h1 + (size_t)db * 32);
    const float4* ghb = (const float4*)(glob_h1 + (size_t)ob * 32);

    float h1a[32], h1b[32];
#pragma unroll
    for (int q = 0; q < 8; q++) {
        float4 dv = dha[q], gv = gha[q];
        h1a[q * 4 + 0] = dv.x + gv.x;
        h1a[q * 4 + 1] = dv.y + gv.y;
        h1a[q * 4 + 2] = dv.z + gv.z;
        h1a[q * 4 + 3] = dv.w + gv.w;
    }
#pragma unroll
    for (int q = 0; q < 8; q++) {
        float4 dv = dhb[q], gv = ghb[q];
        h1b[q * 4 + 0] = dv.x + gv.x;
        h1b[q * 4 + 1] = dv.y + gv.y;
        h1b[q * 4 + 2] = dv.z + gv.z;
        h1b[q * 4 + 3] = dv.w + gv.w;
    }

    // --- layer 1: x phase (5 features), weight shared by both nodes ---
    const float* xra = x + (size_t)ia * 5;
    const float* xrb = x + (size_t)ib * 5;
    float xa0 = xra[0], xa1 = xra[1], xa2 = xra[2], xa3 = xra[3], xa4 = xra[4];
    float xb0 = xrb[0], xb1 = xrb[1], xb2 = xrb[2], xb3 = xrb[3], xb4 = xrb[4];
#pragma unroll
    for (int j = 0; j < 32; j++) {
        float w = W1[j];
        h1a[j] = fmaf(xa0, w, h1a[j]);
        h1b[j] = fmaf(xb0, w, h1b[j]);
    }
#pragma unroll
    for (int j = 0; j < 32; j++) {
        float w = W1[32 + j];
        h1a[j] = fmaf(xa1, w, h1a[j]);
        h1b[j] = fmaf(xb1, w, h1b[j]);
    }
#pragma unroll
    for (int j = 0; j < 32; j++) {
        float w = W1[64 + j];
        h1a[j] = fmaf(xa2, w, h1a[j]);
        h1b[j] = fmaf(xb2, w, h1b[j]);
    }
#pragma unroll
    for (int j = 0; j < 32; j++) {
        float w = W1[96 + j];
        h1a[j] = fmaf(xa3, w, h1a[j]);
        h1b[j] = fmaf(xb3, w, h1b[j]);
    }
#pragma unroll
    for (int j = 0; j < 32; j++) {
        float w = W1[128 + j];
        h1a[j] = fmaf(xa4, w, h1a[j]);
        h1b[j] = fmaf(xb4, w, h1b[j]);
    }

    // --- layer 1: emb phase (k = 5..36), weight shared by both nodes ---
    const float4* era = (const float4*)(emb + (size_t)ia * 32);
    const float4* erb = (const float4*)(emb + (size_t)ib * 32);
#pragma unroll
    for (int q = 0; q < 8; q++) {
        float4 ea = era[q];
        float4 eb = erb[q];
#pragma unroll
        for (int kk = 0; kk < 4; kk++) {
            const int k = 5 + q * 4 + kk;
            const float vva = (kk == 0) ? ea.x : (kk == 1) ? ea.y : (kk == 2) ? ea.z : ea.w;
            const float vvb = (kk == 0) ? eb.x : (kk == 1) ? eb.y : (kk == 2) ? eb.z : eb.w;
#pragma unroll
            for (int j = 0; j < 32; j++) {
                float w = W1[k * 32 + j];
                h1a[j] = fmaf(vva, w, h1a[j]);
                h1b[j] = fmaf(vvb, w, h1b[j]);
            }
        }
    }
#pragma unroll
    for (int j = 0; j < 32; j++) {
        h1a[j] = fmaxf(h1a[j], 0.f);
        h1b[j] = fmaxf(h1b[j], 0.f);
    }

    // --- layer 2: 32 -> 16 ---
    float h2a[16], h2b[16];
#pragma unroll
    for (int j = 0; j < 16; j++) { float bb = b2[j]; h2a[j] = bb; h2b[j] = bb; }
#pragma unroll
    for (int k = 0; k < 32; k++) {
        const float vva = h1a[k];
        const float vvb = h1b[k];
#pragma unroll
        for (int j = 0; j < 16; j++) {
            float w = W2[k * 16 + j];
            h2a[j] = fmaf(vva, w, h2a[j]);
            h2b[j] = fmaf(vvb, w, h2b[j]);
        }
    }
#pragma unroll
    for (int j = 0; j < 16; j++) {
        h2a[j] = fmaxf(h2a[j], 0.f);
        h2b[j] = fmaxf(h2b[j], 0.f);
    }

    // --- layer 3: 16 -> 8 ---
    float h3a[8], h3b[8];
#pragma unroll
    for (int j = 0; j < 8; j++) { float bb = b3[j]; h3a[j] = bb; h3b[j] = bb; }
#pragma unroll
    for (int k = 0; k < 16; k++) {
        const float vva = h2a[k];
        const float vvb = h2b[k];
#pragma unroll
        for (int j = 0; j < 8; j++) {
            float w = W3[k * 8 + j];
            h3a[j] = fmaf(vva, w, h3a[j]);
            h3b[j] = fmaf(vvb, w, h3b[j]);
        }
    }
#pragma unroll
    for (int j = 0; j < 8; j++) {
        h3a[j] = fmaxf(h3a[j], 0.f);
        h3b[j] = fmaxf(h3b[j], 0.f);
    }

    // --- layer 4 ---
    float sa = b4[0], sb = b4[0];
#pragma unroll
    for (int k = 0; k < 8; k++) {
        float w = W4[k];
        sa = fmaf(h3a[k], w, sa);
        sb = fmaf(h3b[k], w, sb);
    }

    const bool livea = va && (mka != 0);
    const bool liveb = vb && (mkb != 0);
    if (va) scores[i0a] = livea ? sa : -FLT_MAX;
    if (vb) scores[i0b] = liveb ? sb : -FLT_MAX;

    // --- merge the thread's pair -> (m, s) ---
    float ma = livea ? sa : -INFINITY;
    float mb = liveb ? sb : -INFINITY;
    float m = fmaxf(ma, mb);
    double sd = 0.0;
    if (ma > -INFINITY) sd += (double)expf(ma - m);
    if (mb > -INFINITY) sd += (double)expf(mb - m);

    // --- wave shuffle reduce, then tiny LDS merge ---
#pragma unroll
    for (int off = 32; off > 0; off >>= 1) {
        float  mo = __shfl_down(m, off);
        double so = __shfl_down(sd, off);
        float M = fmaxf(m, mo);
        double out = 0.0;
        if (m  > -INFINITY) out += sd * (double)expf(m  - M);
        if (mo > -INFINITY) out += so * (double)expf(mo - M);
        m = M; sd = out;
    }
    __shared__ float  mw[BLK / 64];
    __shared__ double sw[BLK / 64];
    const int lane = threadIdx.x & 63, wid = threadIdx.x >> 6;
    if (lane == 0) { mw[wid] = m; sw[wid] = sd; }
    __syncthreads();
    if (threadIdx.x == 0) {
        float M = mw[0]; double S = sw[0];
#pragma unroll
        for (int w = 1; w < BLK / 64; w++) {
            float mbw = mw[w]; double sbw = sw[w];
            float Mn = fmaxf(M, mbw);
            double out = 0.0;
            if (M   > -INFINITY) out += S   * (double)expf(M   - Mn);
            if (mbw > -INFINITY) out += sbw * (double)expf(mbw - Mn);
            M = Mn; S = out;
        }
        blk_m[blockIdx.x] = M;
        blk_s[blockIdx.x] = S;
    }
}

// ---------------------------------------------------------------------------
// K4: merge per-block (m, s) pairs -> gmax, Z. One block.
// ---------------------------------------------------------------------------
__global__ __launch_bounds__(1024) void merge_kernel(
    const float* __restrict__ bm, const double* __restrict__ bs, int n,
    float* __restrict__ gmax, double* __restrict__ Z)
{
    float m = -INFINITY;
    double s = 0.0;
    for (int i = threadIdx.x; i < n; i += 1024) {
        float mb = bm[i]; double sb = bs[i];
        float M = fmaxf(m, mb);
        double out = 0.0;
        if (m  > -INFINITY) out += s  * (double)expf(m  - M);
        if (mb > -INFINITY) out += sb * (double)expf(mb - M);
        m = M; s = out;
    }
    __shared__ float  mred[1024];
    __shared__ double sred[1024];
    mred[threadIdx.x] = m;
    sred[threadIdx.x] = s;
    __syncthreads();
    for (int off = 512; off > 0; off >>= 1) {
        if (threadIdx.x < off) {
            float ma = mred[threadIdx.x], mb = mred[threadIdx.x + off];
            double sa = sred[threadIdx.x], sb = sred[threadIdx.x + off];
            float M = fmaxf(ma, mb);
            double out = 0.0;
            if (ma > -INFINITY) out += sa * (double)expf(ma - M);
            if (mb > -INFINITY) out += sb * (double)expf(mb - M);
            mred[threadIdx.x] = M;
            sred[threadIdx.x] = out;
        }
        __syncthreads();
    }
    if (threadIdx.x == 0) { *gmax = mred[0]; *Z = sred[0]; }
}

// ---------------------------------------------------------------------------
// K5: finalize out[i] = exp(s - gmax) / Z  (masked -FLT_MAX -> exactly 0).
// ---------------------------------------------------------------------------
__global__ __launch_bounds__(BLK) void finalize_kernel(
    const float* __restrict__ scores, int N,
    const float* __restrict__ gmaxp, const double* __restrict__ Zp,
    float* __restrict__ outp)
{
    const float gm = *gmaxp;
    const float rZ = (float)(1.0 / *Zp);
    int i = blockIdx.x * BLK + threadIdx.x;
    if (i < N) outp[i] = expf(scores[i] - gm) * rZ;
}

// ---------------------------------------------------------------------------
extern "C" void kernel_launch(void* const* d_in, const int* in_sizes, int n_in,
                              void* d_out, int out_size, void* d_ws, size_t ws_size,
                              hipStream_t stream)
{
    const float* x        = (const float*)d_in[0];
    const float* emb      = (const float*)d_in[1];
    const float* dag_sum  = (const float*)d_in[2];
    const float* glob_sum = (const float*)d_in[3];
    const int*   dag_cnt  = (const int*)d_in[4];
    const int*   obs_cnt  = (const int*)d_in[5];
    const int*   mask     = (const int*)d_in[6];   // bool staged as int32
    const float* W1 = (const float*)d_in[7];
    const float* b1 = (const float*)d_in[8];
    const float* W2 = (const float*)d_in[9];
    const float* b2 = (const float*)d_in[10];
    const float* W3 = (const float*)d_in[11];
    const float* b3 = (const float*)d_in[12];
    const float* W4 = (const float*)d_in[13];
    const float* b4 = (const float*)d_in[14];
    float* outp = (float*)d_out;

    const int N  = in_sizes[0] / 5;   // 2,000,000
    const int nd = in_sizes[4];       // 20,000
    const int no = in_sizes[5];       // 1,000

    const int main_blocks = (N + 2 * BLK - 1) / (2 * BLK);   // 3907

    // --- workspace layout (16B aligned slices) ---
    char* ws = (char*)d_ws;
    size_t off = 0;
    auto alloc = [&](size_t bytes) {
        void* p = ws + off;
        off += (bytes + 15) & ~(size_t)15;
        return p;
    };
    int*    dag_starts = (int*)   alloc((size_t)(nd + 1) * sizeof(int));
    int*    obs_starts = (int*)   alloc((size_t)(no + 1) * sizeof(int));
    int*    dag_ids    = (int*)   alloc((size_t)N * sizeof(int));
    int*    obs_ids    = (int*)   alloc((size_t)N * sizeof(int));
    float*  dag_h1     = (float*) alloc((size_t)nd * 32 * sizeof(float));
    float*  glob_h1    = (float*) alloc((size_t)no * 32 * sizeof(float));
    float*  scores     = (float*) alloc((size_t)N * sizeof(float));
    float*  blk_m      = (float*) alloc((size_t)main_blocks * sizeof(float));
    double* blk_s      = (double*)alloc((size_t)main_blocks * sizeof(double));
    float*  gmax       = (float*) alloc(sizeof(float));
    double* Z          = (double*)alloc(sizeof(double));
    (void)ws_size;

    // K0: prefix scans
    scan2_kernel<<<1, 1024, 0, stream>>>(dag_cnt, nd, obs_cnt, no, dag_starts, obs_starts);

    // K1: expand segment ids to nodes
    expand_ids_kernel<<<nd + no, 128, 0, stream>>>(dag_starts, nd, obs_starts, no, dag_ids, obs_ids);

    // K2: per-segment layer-1 partials
    {
        int total = (nd + no) * 32;
        seg_h1_kernel<<<(total + 255) / 256, 256, 0, stream>>>(
            dag_sum, nd, glob_sum, no, W1, b1, dag_h1, glob_h1);
    }

    // K3: main MLP + scores + per-block softmax partials (2 nodes/thread)
    mlp_score_kernel<<<main_blocks, BLK, 0, stream>>>(
        x, emb, dag_h1, glob_h1, dag_ids, obs_ids, mask,
        W1, W2, b2, W3, b3, W4, b4, scores, blk_m, blk_s, N);

    // K4: merge -> gmax, Z
    merge_kernel<<<1, 1024, 0, stream>>>(blk_m, blk_s, main_blocks, gmax, Z);

    // K5: finalize
    finalize_kernel<<<(N + BLK - 1) / BLK, BLK, 0, stream>>>(scores, N, gmax, Z, outp);
}